// Round 13
// baseline (257.938 us; speedup 1.0000x reference)
//
#include <hip/hip_runtime.h>

#define D 128
#define EPS 1e-5f
#define SCAN_CHUNK 1024   // elements per scan block (256 thr x 4)
#define TSTRIDE 136       // LDS tile row stride in shorts (272 B = 17*16 -> 16B aligned, 2-way banks)
#define FIXSCALE 1099511627776.0f       // 2^40
#define INVFIXSCALE (1.0f / 1099511627776.0f)

typedef __attribute__((ext_vector_type(8))) short bf16x8;
typedef __attribute__((ext_vector_type(4))) float floatx4;

// fp32 -> bf16 round-to-nearest-even
__device__ __forceinline__ unsigned short f2bf(float f) {
    union { float f; unsigned u; } v; v.f = f;
    unsigned r = v.u + 0x7fffu + ((v.u >> 16) & 1u);
    return (unsigned short)(r >> 16);
}
__device__ __forceinline__ float bf2f(unsigned short s) {
    union { unsigned u; float f; } v; v.u = ((unsigned)s) << 16; return v.f;
}

// ---------------- prep: weights -> bf16 Wt[f][k]; zero counts; offsets[nN]=nE ----------------
__global__ __launch_bounds__(256) void prep(const float* __restrict__ W0,
                                            const float* __restrict__ W1,
                                            const float* __restrict__ W2,
                                            unsigned short* __restrict__ wt,
                                            int* __restrict__ counts,
                                            int* __restrict__ offsets, int nN, int nE) {
    int idx = blockIdx.x * 256 + threadIdx.x;
    if (idx < 3 * D * D) {
        int w = idx >> 14;
        int r = idx & (D * D - 1);
        int f = r >> 7, k = r & (D - 1);
        const float* W = (w == 0) ? W0 : (w == 1) ? W1 : W2;
        wt[(size_t)w * D * D + (size_t)f * D + k] = f2bf(W[(size_t)k * D + f]);
    }
    if (idx < nN) counts[idx] = 0;
    if (idx == 0) offsets[nN] = nE;
}

// ---------------- GEMM1 + dst-histogram fused in one dispatch ----------------
// Interleaved block roles: (blockIdx%4)==3 -> histogram (grid-stride over edges),
// else gemm1 tile. Both kinds co-reside per CU: atomic-latency waves overlap MFMA waves.
__global__ __launch_bounds__(256) void gemm1_hist(const float* __restrict__ X,
                                                  const unsigned short* __restrict__ Wt,
                                                  const float* __restrict__ bias,
                                                  unsigned short* __restrict__ Y, int nrows,
                                                  const int* __restrict__ dst,
                                                  int* __restrict__ counts, int nE, int HB) {
    const int bid = blockIdx.x;
    const int r = bid >> 2, c = bid & 3;

    if (c == 3) {
        // ---- histogram role: HB blocks, grid-stride over edges ----
        const int stride = HB * 256;
        for (int e = r * 256 + threadIdx.x; e < nE; e += stride)
            atomicAdd(&counts[dst[e]], 1);
        return;
    }

    // ---- gemm role: tile index 3*r + c ----
    const int tile = 3 * r + c;
    const int gblocks = (nrows + 63) / 64;
    if (tile >= gblocks) return;

    const int t = threadIdx.x;
    const int lane = t & 63, wave = t >> 6;
    const int g = wave >> 1, hf = wave & 1;
    const int ml = lane & 15, q = lane >> 4;
    const int n0 = tile * 64 + g * 32 + ml;
    const int n1 = n0 + 16;
    const int rr0 = (n0 < nrows) ? n0 : (nrows - 1);
    const int rr1 = (n1 < nrows) ? n1 : (nrows - 1);
    const bool ok0 = (n0 < nrows), ok1 = (n1 < nrows);

    bf16x8 bf0[4], bf1[4];
    {
        const float* x0 = X + (size_t)rr0 * D + q * 8;
        const float* x1 = X + (size_t)rr1 * D + q * 8;
#pragma unroll
        for (int kb = 0; kb < 4; ++kb) {
            float4 a0 = *(const float4*)(x0 + kb * 32);
            float4 a1 = *(const float4*)(x0 + kb * 32 + 4);
            float4 c0 = *(const float4*)(x1 + kb * 32);
            float4 c1 = *(const float4*)(x1 + kb * 32 + 4);
            bf16x8 v0, v1;
            v0[0] = (short)f2bf(a0.x); v0[1] = (short)f2bf(a0.y);
            v0[2] = (short)f2bf(a0.z); v0[3] = (short)f2bf(a0.w);
            v0[4] = (short)f2bf(a1.x); v0[5] = (short)f2bf(a1.y);
            v0[6] = (short)f2bf(a1.z); v0[7] = (short)f2bf(a1.w);
            v1[0] = (short)f2bf(c0.x); v1[1] = (short)f2bf(c0.y);
            v1[2] = (short)f2bf(c0.z); v1[3] = (short)f2bf(c0.w);
            v1[4] = (short)f2bf(c1.x); v1[5] = (short)f2bf(c1.y);
            v1[6] = (short)f2bf(c1.z); v1[7] = (short)f2bf(c1.w);
            bf0[kb] = v0; bf1[kb] = v1;
        }
    }

#pragma unroll
    for (int tl2 = 0; tl2 < 4; ++tl2) {
        const int tl = hf * 4 + tl2;
        floatx4 ac0 = {0.f, 0.f, 0.f, 0.f};
        floatx4 ac1 = {0.f, 0.f, 0.f, 0.f};
        const unsigned short* wp = Wt + (size_t)(tl * 16 + ml) * D + q * 8;
#pragma unroll
        for (int kb = 0; kb < 4; ++kb) {
            bf16x8 af = *(const bf16x8*)(wp + kb * 32);
            ac0 = __builtin_amdgcn_mfma_f32_16x16x32_bf16(af, bf0[kb], ac0, 0, 0, 0);
            ac1 = __builtin_amdgcn_mfma_f32_16x16x32_bf16(af, bf1[kb], ac1, 0, 0, 0);
        }
        const int f0i = tl * 16 + q * 4;
        float4 b4 = *(const float4*)(bias + f0i);
        if (ok0) {
            ushort4 o;
            o.x = f2bf(ac0[0] + b4.x); o.y = f2bf(ac0[1] + b4.y);
            o.z = f2bf(ac0[2] + b4.z); o.w = f2bf(ac0[3] + b4.w);
            *(ushort4*)(Y + (size_t)n0 * D + f0i) = o;
        }
        if (ok1) {
            ushort4 o;
            o.x = f2bf(ac1[0] + b4.x); o.y = f2bf(ac1[1] + b4.y);
            o.z = f2bf(ac1[2] + b4.z); o.w = f2bf(ac1[3] + b4.w);
            *(ushort4*)(Y + (size_t)n1 * D + f0i) = o;
        }
    }
}

// ---------------- one-kernel scan: each block sums its full prefix, then chunk-scans ----------
__global__ __launch_bounds__(256) void scan_all(const int* __restrict__ counts,
                                                int* __restrict__ offsets,
                                                int* __restrict__ cursor, int n) {
    __shared__ int sh[256];
    __shared__ int sbase_sh;
    const int t = threadIdx.x;
    const int base0 = blockIdx.x * SCAN_CHUNK;

    // block-wide sum of counts[0 .. base0) (L2-resident; <=49k ints)
    int ps = 0;
    for (int i = t; i < base0; i += 256) ps += counts[i];
    sh[t] = ps;
    __syncthreads();
    for (int off = 128; off > 0; off >>= 1) {
        if (t < off) sh[t] += sh[t + off];
        __syncthreads();
    }
    if (t == 0) sbase_sh = sh[0];
    __syncthreads();
    const int sbase = sbase_sh;
    __syncthreads();   // sh about to be reused

    const int base = base0 + t * 4;
    int c[4];
    int s = 0;
#pragma unroll
    for (int i = 0; i < 4; ++i) {
        int idx = base + i;
        c[i] = (idx < n) ? counts[idx] : 0;
        s += c[i];
    }
    sh[t] = s;
    __syncthreads();
    int val = s;
    for (int off = 1; off < 256; off <<= 1) {
        int u = (t >= off) ? sh[t - off] : 0;
        __syncthreads();
        val += u;
        sh[t] = val;
        __syncthreads();
    }
    int run = val - s + sbase;
#pragma unroll
    for (int i = 0; i < 4; ++i) {
        int idx = base + i;
        if (idx < n) {
            offsets[idx] = run;
            cursor[idx] = run;
        }
        run += c[i];
    }
}

__global__ __launch_bounds__(256) void fill_edges(const int* __restrict__ src,
                                                  const int* __restrict__ dst,
                                                  int* __restrict__ cursor,
                                                  int* __restrict__ edge_src, int nE) {
    int e = blockIdx.x * 256 + threadIdx.x;
    if (e < nE) {
        int pos = atomicAdd(&cursor[dst[e]], 1);
        edge_src[pos] = src[e];
    }
}

// ---------------- gather segment-sum: agg[n] = sum hpre[edge_src[j]] ---------------------
// DETERMINISM: fill_edges permutes each bucket nondeterministically (atomic order). We
// accumulate in int64 fixed-point (scale 2^40) — associative/commutative, so the sum is
// bit-identical under any edge permutation (graph-replay tripwire safe). Quantization
// error ~2^-41/elem, invisible at bf16 output granularity.
// 16 lanes/node, 16 nodes/block -> 50000 concurrent streams; unroll-4 row loads in flight.
__global__ __launch_bounds__(256) void gather_sum(const unsigned short* __restrict__ hpre,
                                                  const int* __restrict__ offsets,
                                                  const int* __restrict__ edge_src,
                                                  unsigned short* __restrict__ agg, int nN) {
    const int t = threadIdx.x;
    const int li = t & 15;
    const int n = blockIdx.x * 16 + (t >> 4);
    if (n >= nN) return;
    const int beg = offsets[n], end = offsets[n + 1];

    long long a[8] = {0, 0, 0, 0, 0, 0, 0, 0};
    int j = beg;
    while (j + 4 <= end) {
        const int i0 = edge_src[j], i1 = edge_src[j + 1];
        const int i2 = edge_src[j + 2], i3 = edge_src[j + 3];
        bf16x8 v0 = *(const bf16x8*)(hpre + (size_t)i0 * D + li * 8);
        bf16x8 v1 = *(const bf16x8*)(hpre + (size_t)i1 * D + li * 8);
        bf16x8 v2 = *(const bf16x8*)(hpre + (size_t)i2 * D + li * 8);
        bf16x8 v3 = *(const bf16x8*)(hpre + (size_t)i3 * D + li * 8);
#pragma unroll
        for (int i = 0; i < 8; ++i) {
            a[i] += llrintf(bf2f((unsigned short)v0[i]) * FIXSCALE)
                  + llrintf(bf2f((unsigned short)v1[i]) * FIXSCALE)
                  + llrintf(bf2f((unsigned short)v2[i]) * FIXSCALE)
                  + llrintf(bf2f((unsigned short)v3[i]) * FIXSCALE);
        }
        j += 4;
    }
    while (j < end) {
        const int i0 = edge_src[j++];
        bf16x8 v0 = *(const bf16x8*)(hpre + (size_t)i0 * D + li * 8);
#pragma unroll
        for (int i = 0; i < 8; ++i)
            a[i] += llrintf(bf2f((unsigned short)v0[i]) * FIXSCALE);
    }

    bf16x8 p;
#pragma unroll
    for (int i = 0; i < 8; ++i) p[i] = (short)f2bf((float)a[i] * INVFIXSCALE);
    *(bf16x8*)(agg + (size_t)n * D + li * 8) = p;
}

// ---------------- fused MLP: GEMM2(relu) -> GEMM3 -> +res -> LayerNorm ----------------
// Block = 4 waves = 64 nodes. Wave(g,hf): nodes g*32+ml, g*32+16+ml; tile half hf.
// 2 B-frags per wave share each weight A-load; t1 via LDS; LN halves combined via LDS.
__global__ __launch_bounds__(256) void fused_mlp(const unsigned short* __restrict__ agg,
                                                 const unsigned short* __restrict__ hpre,
                                                 const unsigned short* __restrict__ Wt1,
                                                 const float* __restrict__ b1,
                                                 const unsigned short* __restrict__ Wt2,
                                                 const float* __restrict__ b2,
                                                 const float* __restrict__ gamma,
                                                 const float* __restrict__ beta,
                                                 float* __restrict__ out, int nN) {
    __shared__ unsigned short tile[64 * TSTRIDE];   // 17.4 KB
    __shared__ float psm[2][64], psq[2][64];
    const int t = threadIdx.x;
    const int lane = t & 63, wave = t >> 6;
    const int g = wave >> 1, hf = wave & 1;
    const int ml = lane & 15, q = lane >> 4;
    const int lr0 = g * 32 + ml, lr1 = lr0 + 16;
    const int n0 = blockIdx.x * 64 + lr0;
    const int n1 = blockIdx.x * 64 + lr1;
    const int rr0 = (n0 < nN) ? n0 : (nN - 1);
    const int rr1 = (n1 < nN) ? n1 : (nN - 1);
    const bool ok0 = (n0 < nN), ok1 = (n1 < nN);

    // ---- GEMM2 (half): t1 features hf*64..hf*64+63 for both nodes -> LDS tile ----
    {
        bf16x8 bf0[4], bf1[4];
        const unsigned short* x0 = agg + (size_t)rr0 * D + q * 8;
        const unsigned short* x1 = agg + (size_t)rr1 * D + q * 8;
#pragma unroll
        for (int kb = 0; kb < 4; ++kb) {
            bf0[kb] = *(const bf16x8*)(x0 + kb * 32);
            bf1[kb] = *(const bf16x8*)(x1 + kb * 32);
        }

#pragma unroll
        for (int tl2 = 0; tl2 < 4; ++tl2) {
            const int tl = hf * 4 + tl2;
            floatx4 ac0 = {0.f, 0.f, 0.f, 0.f};
            floatx4 ac1 = {0.f, 0.f, 0.f, 0.f};
            const unsigned short* wp = Wt1 + (size_t)(tl * 16 + ml) * D + q * 8;
#pragma unroll
            for (int kb = 0; kb < 4; ++kb) {
                bf16x8 af = *(const bf16x8*)(wp + kb * 32);
                ac0 = __builtin_amdgcn_mfma_f32_16x16x32_bf16(af, bf0[kb], ac0, 0, 0, 0);
                ac1 = __builtin_amdgcn_mfma_f32_16x16x32_bf16(af, bf1[kb], ac1, 0, 0, 0);
            }
            const int f0i = tl * 16 + q * 4;
            float4 b4 = *(const float4*)(b1 + f0i);
            ushort4 o0, o1;
            o0.x = f2bf(fmaxf(ac0[0] + b4.x, 0.f));
            o0.y = f2bf(fmaxf(ac0[1] + b4.y, 0.f));
            o0.z = f2bf(fmaxf(ac0[2] + b4.z, 0.f));
            o0.w = f2bf(fmaxf(ac0[3] + b4.w, 0.f));
            o1.x = f2bf(fmaxf(ac1[0] + b4.x, 0.f));
            o1.y = f2bf(fmaxf(ac1[1] + b4.y, 0.f));
            o1.z = f2bf(fmaxf(ac1[2] + b4.z, 0.f));
            o1.w = f2bf(fmaxf(ac1[3] + b4.w, 0.f));
            *(ushort4*)(&tile[lr0 * TSTRIDE + f0i]) = o0;
            *(ushort4*)(&tile[lr1 * TSTRIDE + f0i]) = o1;
        }
    }
    __syncthreads();

    // ---- GEMM3 (half) + residual; partial LN sums ----
    float vs0[4][4], vs1[4][4];
    {
        bf16x8 bf0[4], bf1[4];
#pragma unroll
        for (int kb = 0; kb < 4; ++kb) {
            bf0[kb] = *(const bf16x8*)(&tile[lr0 * TSTRIDE + kb * 32 + q * 8]);
            bf1[kb] = *(const bf16x8*)(&tile[lr1 * TSTRIDE + kb * 32 + q * 8]);
        }

        float sm0 = 0.f, sq0 = 0.f, sm1 = 0.f, sq1 = 0.f;
#pragma unroll
        for (int tl2 = 0; tl2 < 4; ++tl2) {
            const int tl = hf * 4 + tl2;
            floatx4 ac0 = {0.f, 0.f, 0.f, 0.f};
            floatx4 ac1 = {0.f, 0.f, 0.f, 0.f};
            const unsigned short* wp = Wt2 + (size_t)(tl * 16 + ml) * D + q * 8;
#pragma unroll
            for (int kb = 0; kb < 4; ++kb) {
                bf16x8 af = *(const bf16x8*)(wp + kb * 32);
                ac0 = __builtin_amdgcn_mfma_f32_16x16x32_bf16(af, bf0[kb], ac0, 0, 0, 0);
                ac1 = __builtin_amdgcn_mfma_f32_16x16x32_bf16(af, bf1[kb], ac1, 0, 0, 0);
            }
            const int f0i = tl * 16 + q * 4;
            float4 b4 = *(const float4*)(b2 + f0i);
            ushort4 h0 = ((const ushort4*)(hpre + (size_t)rr0 * D + f0i))[0];
            ushort4 h1 = ((const ushort4*)(hpre + (size_t)rr1 * D + f0i))[0];
            float a0 = fmaxf(ac0[0] + b4.x, 0.f) + bf2f(h0.x);
            float a1 = fmaxf(ac0[1] + b4.y, 0.f) + bf2f(h0.y);
            float a2 = fmaxf(ac0[2] + b4.z, 0.f) + bf2f(h0.z);
            float a3 = fmaxf(ac0[3] + b4.w, 0.f) + bf2f(h0.w);
            float c0 = fmaxf(ac1[0] + b4.x, 0.f) + bf2f(h1.x);
            float c1 = fmaxf(ac1[1] + b4.y, 0.f) + bf2f(h1.y);
            float c2 = fmaxf(ac1[2] + b4.z, 0.f) + bf2f(h1.z);
            float c3 = fmaxf(ac1[3] + b4.w, 0.f) + bf2f(h1.w);
            vs0[tl2][0] = a0; vs0[tl2][1] = a1; vs0[tl2][2] = a2; vs0[tl2][3] = a3;
            vs1[tl2][0] = c0; vs1[tl2][1] = c1; vs1[tl2][2] = c2; vs1[tl2][3] = c3;
            sm0 += a0 + a1 + a2 + a3;
            sq0 += a0 * a0 + a1 * a1 + a2 * a2 + a3 * a3;
            sm1 += c0 + c1 + c2 + c3;
            sq1 += c0 * c0 + c1 * c1 + c2 * c2 + c3 * c3;
        }
        sm0 += __shfl_xor(sm0, 16); sm0 += __shfl_xor(sm0, 32);
        sq0 += __shfl_xor(sq0, 16); sq0 += __shfl_xor(sq0, 32);
        sm1 += __shfl_xor(sm1, 16); sm1 += __shfl_xor(sm1, 32);
        sq1 += __shfl_xor(sq1, 16); sq1 += __shfl_xor(sq1, 32);
        if (lane < 16) {
            psm[hf][lr0] = sm0; psq[hf][lr0] = sq0;
            psm[hf][lr1] = sm1; psq[hf][lr1] = sq1;
        }
    }
    __syncthreads();

    // ---- combine halves, normalize, write ----
    {
        const float smT0 = psm[0][lr0] + psm[1][lr0];
        const float sqT0 = psq[0][lr0] + psq[1][lr0];
        const float smT1 = psm[0][lr1] + psm[1][lr1];
        const float sqT1 = psq[0][lr1] + psq[1][lr1];
        const float mu0 = smT0 * (1.f / D);
        const float is0 = rsqrtf(sqT0 * (1.f / D) - mu0 * mu0 + EPS);
        const float mu1 = smT1 * (1.f / D);
        const float is1 = rsqrtf(sqT1 * (1.f / D) - mu1 * mu1 + EPS);

#pragma unroll
        for (int tl2 = 0; tl2 < 4; ++tl2) {
            const int f0i = (hf * 4 + tl2) * 16 + q * 4;
            float4 g4 = *(const float4*)(gamma + f0i);
            float4 be4 = *(const float4*)(beta + f0i);
            if (ok0) {
                float4 o;
                o.x = (vs0[tl2][0] - mu0) * is0 * g4.x + be4.x;
                o.y = (vs0[tl2][1] - mu0) * is0 * g4.y + be4.y;
                o.z = (vs0[tl2][2] - mu0) * is0 * g4.z + be4.z;
                o.w = (vs0[tl2][3] - mu0) * is0 * g4.w + be4.w;
                *(float4*)(out + (size_t)n0 * D + f0i) = o;
            }
            if (ok1) {
                float4 o;
                o.x = (vs1[tl2][0] - mu1) * is1 * g4.x + be4.x;
                o.y = (vs1[tl2][1] - mu1) * is1 * g4.y + be4.y;
                o.z = (vs1[tl2][2] - mu1) * is1 * g4.z + be4.z;
                o.w = (vs1[tl2][3] - mu1) * is1 * g4.w + be4.w;
                *(float4*)(out + (size_t)n1 * D + f0i) = o;
            }
        }
    }
}

extern "C" void kernel_launch(void* const* d_in, const int* in_sizes, int n_in,
                              void* d_out, int out_size, void* d_ws, size_t ws_size,
                              hipStream_t stream) {
    const float* h     = (const float*)d_in[0];
    const int*   src   = (const int*)d_in[1];
    const int*   dst   = (const int*)d_in[2];
    const float* W_pre = (const float*)d_in[3];
    const float* b_pre = (const float*)d_in[4];
    const float* W1    = (const float*)d_in[5];
    const float* b1    = (const float*)d_in[6];
    const float* W2    = (const float*)d_in[7];
    const float* b2    = (const float*)d_in[8];
    const float* gamma = (const float*)d_in[9];
    const float* beta  = (const float*)d_in[10];
    float* out = (float*)d_out;

    const int nN = in_sizes[0] / D;   // 50000
    const int nE = in_sizes[1];       // 600000
    const size_t rowsz = (size_t)nN * D;

    // ---- workspace layout ----
    unsigned short* hpre = (unsigned short*)d_ws;      // [nN*D] bf16
    unsigned short* agg  = hpre + rowsz;               // [nN*D] bf16
    unsigned short* wt   = agg + rowsz;                // [3*D*D] bf16
    int* edge_src  = (int*)(wt + 3 * D * D);           // [nE]
    int* offsets   = edge_src + nE;                    // [nN+1]
    int* cursor    = offsets + nN + 1;                 // [nN]
    int* counts    = cursor + nN;                      // [nN]

    const int prep_n  = (3 * D * D > nN) ? 3 * D * D : nN;
    const int eblocks = (nE + 255) / 256;
    const int gblocks = (nN + 63) / 64;                       // 782 gemm tiles
    const int HB      = (gblocks + 2) / 3;                    // 261 hist blocks (1:3 interleave)
    const int cgrid   = 4 * HB;                               // 1044 combined blocks
    const int nChunks = (nN + SCAN_CHUNK - 1) / SCAN_CHUNK;   // 49

    prep<<<(prep_n + 255) / 256, 256, 0, stream>>>(W_pre, W1, W2, wt, counts, offsets, nN, nE);
    gemm1_hist<<<cgrid, 256, 0, stream>>>(h, wt, b_pre, hpre, nN, dst, counts, nE, HB);
    scan_all<<<nChunks, 256, 0, stream>>>(counts, offsets, cursor, nN);
    fill_edges<<<eblocks, 256, 0, stream>>>(src, dst, cursor, edge_src, nE);
    gather_sum<<<(nN + 15) / 16, 256, 0, stream>>>(hpre, offsets, edge_src, agg, nN);
    fused_mlp<<<gblocks, 256, 0, stream>>>(agg, hpre, wt + D * D, b1, wt + 2 * D * D, b2,
                                           gamma, beta, out, nN);
}